// Round 1
// baseline (1829.241 us; speedup 1.0000x reference)
//
#include <hip/hip_runtime.h>
#include <hip/hip_bf16.h>
#include <math.h>

// Problem constants
#define BB 2
#define TT 2048
#define DD 1024
#define HH 8
#define SS 128
#define HDD 128
#define LVV 12
#define MM (BB*TT)   // 4096

__device__ __forceinline__ float softplus_f(float z) {
  // stable: max(z,0) + log1p(exp(-|z|))
  return fmaxf(z, 0.f) + log1pf(expf(-fabsf(z)));
}

// ---------------- GEMM: C = A[M,K] @ W[N,K]^T, fp32, 128x128 tile ----------------
// mode 0: C[m*N + n]
// mode 1: head-split: C[((b*8 + n>>7)*2048 + (m&2047))*128 + (n&127)], b = m>>11
__global__ __launch_bounds__(256) void gemm_xwT(
    const float* __restrict__ A, const float* __restrict__ W,
    float* __restrict__ C, int M, int N, int K, int mode) {
  __shared__ float As[16][132];
  __shared__ float Bs[16][132];
  const int tid = threadIdx.x;
  const int bm = blockIdx.y * 128;
  const int bn = blockIdx.x * 128;
  const int tx = tid & 15, ty = tid >> 4;
  const int lr = tid >> 2;          // 0..63
  const int lk = (tid & 3) << 2;    // 0,4,8,12
  float acc[8][8] = {};
  for (int k0 = 0; k0 < K; k0 += 16) {
    float4 a0 = *(const float4*)&A[(size_t)(bm + lr) * K + k0 + lk];
    float4 a1 = *(const float4*)&A[(size_t)(bm + lr + 64) * K + k0 + lk];
    float4 b0 = *(const float4*)&W[(size_t)(bn + lr) * K + k0 + lk];
    float4 b1 = *(const float4*)&W[(size_t)(bn + lr + 64) * K + k0 + lk];
    __syncthreads();
    As[lk+0][lr] = a0.x; As[lk+1][lr] = a0.y; As[lk+2][lr] = a0.z; As[lk+3][lr] = a0.w;
    As[lk+0][lr+64] = a1.x; As[lk+1][lr+64] = a1.y; As[lk+2][lr+64] = a1.z; As[lk+3][lr+64] = a1.w;
    Bs[lk+0][lr] = b0.x; Bs[lk+1][lr] = b0.y; Bs[lk+2][lr] = b0.z; Bs[lk+3][lr] = b0.w;
    Bs[lk+0][lr+64] = b1.x; Bs[lk+1][lr+64] = b1.y; Bs[lk+2][lr+64] = b1.z; Bs[lk+3][lr+64] = b1.w;
    __syncthreads();
    #pragma unroll
    for (int kk = 0; kk < 16; ++kk) {
      float av[8], bv[8];
      #pragma unroll
      for (int i = 0; i < 8; ++i) av[i] = As[kk][ty*8+i];
      #pragma unroll
      for (int j = 0; j < 8; ++j) bv[j] = Bs[kk][tx*8+j];
      #pragma unroll
      for (int i = 0; i < 8; ++i)
        #pragma unroll
        for (int j = 0; j < 8; ++j)
          acc[i][j] += av[i] * bv[j];
    }
  }
  if (mode == 0) {
    #pragma unroll
    for (int i = 0; i < 8; ++i)
      #pragma unroll
      for (int j = 0; j < 8; ++j)
        C[(size_t)(bm + ty*8 + i) * N + (bn + tx*8 + j)] = acc[i][j];
  } else {
    #pragma unroll
    for (int i = 0; i < 8; ++i) {
      int m = bm + ty*8 + i;
      int b = m >> 11, t = m & 2047;
      #pragma unroll
      for (int j = 0; j < 8; ++j) {
        int n = bn + tx*8 + j;
        int h = n >> 7, d = n & 127;
        C[(((size_t)(b*8 + h) * 2048 + t) << 7) + d] = acc[i][j];
      }
    }
  }
}

// ---------------- small projections: g (pre-cumsum) and lambda ----------------
// One block per row m (B*T rows). Computes g = -softplus(x@Wg^T + bg) into G[(b*8+h)*T + t]
// and lam = softplus(x@Wdl^T + Lparam) into lam[((b*8+h)*T + t)*12 + l].
__global__ __launch_bounds__(128) void proj_gl(
    const float* __restrict__ x, const float* __restrict__ Wg,
    const float* __restrict__ bg, const float* __restrict__ Wdl,
    const float* __restrict__ Lp, float* __restrict__ Gout,
    float* __restrict__ lamout) {
  __shared__ float xs[1024];
  const int m = blockIdx.x;
  const int tid = threadIdx.x;
  #pragma unroll
  for (int p = 0; p < 2; ++p) {
    float4 v = *(const float4*)&x[(size_t)m * 1024 + (tid + p*128) * 4];
    *(float4*)&xs[(tid + p*128) * 4] = v;
  }
  __syncthreads();
  if (tid < 104) {
    const float* wr = (tid < 8) ? &Wg[(size_t)tid * 1024] : &Wdl[(size_t)(tid - 8) * 1024];
    float dot = 0.f;
    for (int kk = 0; kk < 256; ++kk) {
      float4 w = *(const float4*)&wr[kk * 4];
      float4 xv = *(const float4*)&xs[kk * 4];
      dot += w.x*xv.x + w.y*xv.y + w.z*xv.z + w.w*xv.w;
    }
    int b = m >> 11, t = m & 2047;
    if (tid < 8) {
      float z = dot + bg[tid];
      Gout[(size_t)(b*8 + tid) * 2048 + t] = -softplus_f(z);
    } else {
      int c = tid - 8;
      int h = c / 12, l = c % 12;
      float z = dot + Lp[h*12 + l];
      lamout[((size_t)(b*8 + h) * 2048 + t) * 12 + l] = softplus_f(z);
    }
  }
}

// ---------------- inclusive cumsum over T per (b,h) ----------------
__global__ __launch_bounds__(256) void cumsum_k(float* __restrict__ G) {
  __shared__ float csum[256];
  const int bh = blockIdx.x;
  const int tid = threadIdx.x;
  float* Gr = G + (size_t)bh * 2048;
  float vals[8];
  float s = 0.f;
  #pragma unroll
  for (int j = 0; j < 8; ++j) { vals[j] = Gr[tid*8 + j]; s += vals[j]; }
  csum[tid] = s;
  __syncthreads();
  if (tid == 0) {
    float run = 0.f;
    for (int i = 0; i < 256; ++i) { float t = csum[i]; csum[i] = run; run += t; }
  }
  __syncthreads();
  float run = csum[tid];
  #pragma unroll
  for (int j = 0; j < 8; ++j) { run += vals[j]; Gr[tid*8 + j] = run; }
}

// ---------------- attention: per (b,h), 32-query tiles over causal key tiles ----------------
// q,k,v: [B*H, T, 128]; G: [B*H, T]; lam: [B*H, T, 12]; y out: [B, T, H*128]
__global__ __launch_bounds__(256) void attn_k(
    const float* __restrict__ q, const float* __restrict__ k,
    const float* __restrict__ v, const float* __restrict__ G,
    const float* __restrict__ lam, float* __restrict__ y) {
  __shared__ float qs[32][132];
  __shared__ float ks[32][132];
  __shared__ float vs[32][132];
  __shared__ float Atile[32][33];
  __shared__ float Gq[32], Gs[32];
  __shared__ float lamq[32][12];
  const int tid = threadIdx.x;
  const int qt = (int)(gridDim.x - 1 - blockIdx.x);   // heavy tiles first
  const int bh = blockIdx.y;
  const int t0 = qt * 32;
  const float* qb = q + (size_t)bh * 2048 * 128;
  const float* kb = k + (size_t)bh * 2048 * 128;
  const float* vb = v + (size_t)bh * 2048 * 128;
  const float* Gb = G + (size_t)bh * 2048;
  const float* lamb = lam + (size_t)bh * 2048 * 12;

  {
    int row = tid >> 3, c8 = tid & 7;
    #pragma unroll
    for (int p = 0; p < 4; ++p) {
      int cf = (c8 + p*8) * 4;
      float4 qv = *(const float4*)&qb[(size_t)(t0 + row) * 128 + cf];
      qs[row][cf] = qv.x; qs[row][cf+1] = qv.y; qs[row][cf+2] = qv.z; qs[row][cf+3] = qv.w;
    }
  }
  if (tid < 32) Gq[tid] = Gb[t0 + tid];
  for (int i = tid; i < 32*12; i += 256) lamq[i/12][i%12] = lamb[(size_t)t0*12 + i];

  const int tt = tid >> 3;   // query row 0..31
  const int sg = tid & 7;    // 0..7
  float acc[16] = {};
  const float scale = 0.08838834764831845f;  // 1/sqrt(128)

  for (int st = 0; st <= qt; ++st) {
    const int s0 = st * 32;
    __syncthreads();   // prior PV done before overwriting ks/vs
    {
      int row = tid >> 3, c8 = tid & 7;
      #pragma unroll
      for (int p = 0; p < 4; ++p) {
        int cf = (c8 + p*8) * 4;
        float4 kv = *(const float4*)&kb[(size_t)(s0 + row) * 128 + cf];
        ks[row][cf] = kv.x; ks[row][cf+1] = kv.y; ks[row][cf+2] = kv.z; ks[row][cf+3] = kv.w;
        float4 vv = *(const float4*)&vb[(size_t)(s0 + row) * 128 + cf];
        vs[row][cf] = vv.x; vs[row][cf+1] = vv.y; vs[row][cf+2] = vv.z; vs[row][cf+3] = vv.w;
      }
      if (tid < 32) Gs[tid] = Gb[s0 + tid];
    }
    __syncthreads();
    // scores: each thread does 4 (tt, s) pairs
    float dots[4] = {};
    for (int kk = 0; kk < 128; ++kk) {
      float qv = qs[tt][kk];
      dots[0] += qv * ks[sg*4 + 0][kk];
      dots[1] += qv * ks[sg*4 + 1][kk];
      dots[2] += qv * ks[sg*4 + 2][kk];
      dots[3] += qv * ks[sg*4 + 3][kk];
    }
    #pragma unroll
    for (int i = 0; i < 4; ++i) {
      int s = sg*4 + i;
      int dts = (t0 + tt) - (s0 + s);
      float a = 0.f;
      if (dts >= 0) {
        int lvl = (dts == 0) ? 0 : min(32 - __clz(dts), 11);
        a = dots[i] * scale * expf(Gq[tt] - Gs[s]) * lamq[tt][lvl];
      }
      Atile[tt][s] = a;
    }
    __syncthreads();
    // PV: thread owns (tt, d = j*8 + sg)
    #pragma unroll 8
    for (int ss = 0; ss < 32; ++ss) {
      float a = Atile[tt][ss];
      #pragma unroll
      for (int j = 0; j < 16; ++j)
        acc[j] += a * vs[ss][j*8 + sg];
    }
  }
  // write y[B, T, H*128]
  const int b = bh >> 3, h = bh & 7;
  float* yr = y + ((size_t)(b*2048 + t0 + tt) * 1024) + h*128;
  #pragma unroll
  for (int j = 0; j < 16; ++j) yr[j*8 + sg] = acc[j];
}

// ---------------- residual + LayerNorm ----------------
__global__ __launch_bounds__(256) void ln_k(
    const float* __restrict__ op, const float* __restrict__ x,
    const float* __restrict__ g, const float* __restrict__ b,
    float* __restrict__ out) {
  const int m = blockIdx.x;
  const int tid = threadIdx.x;
  float4 o = *(const float4*)&op[(size_t)m*1024 + tid*4];
  float4 xv = *(const float4*)&x[(size_t)m*1024 + tid*4];
  float v0 = o.x + xv.x, v1 = o.y + xv.y, v2 = o.z + xv.z, v3 = o.w + xv.w;
  float s1 = v0 + v1 + v2 + v3;
  float s2 = v0*v0 + v1*v1 + v2*v2 + v3*v3;
  #pragma unroll
  for (int off = 32; off >= 1; off >>= 1) {
    s1 += __shfl_down(s1, off);
    s2 += __shfl_down(s2, off);
  }
  __shared__ float r1[4], r2[4];
  if ((tid & 63) == 0) { r1[tid >> 6] = s1; r2[tid >> 6] = s2; }
  __syncthreads();
  float S1 = r1[0] + r1[1] + r1[2] + r1[3];
  float S2 = r2[0] + r2[1] + r2[2] + r2[3];
  float mu = S1 * (1.f/1024.f);
  float var = S2 * (1.f/1024.f) - mu*mu;
  float rs = rsqrtf(var + 1e-5f);
  float4 gg = *(const float4*)&g[tid*4];
  float4 bb = *(const float4*)&b[tid*4];
  float4 r;
  r.x = (v0 - mu) * rs * gg.x + bb.x;
  r.y = (v1 - mu) * rs * gg.y + bb.y;
  r.z = (v2 - mu) * rs * gg.z + bb.z;
  r.w = (v3 - mu) * rs * gg.w + bb.w;
  *(float4*)&out[(size_t)m*1024 + tid*4] = r;
}

extern "C" void kernel_launch(void* const* d_in, const int* in_sizes, int n_in,
                              void* d_out, int out_size, void* d_ws, size_t ws_size,
                              hipStream_t stream) {
  const float* x   = (const float*)d_in[0];
  const float* Wq  = (const float*)d_in[1];
  const float* Wk  = (const float*)d_in[2];
  const float* Wv  = (const float*)d_in[3];
  const float* Wg  = (const float*)d_in[4];
  const float* bg  = (const float*)d_in[5];
  const float* Wdl = (const float*)d_in[6];
  const float* Lp  = (const float*)d_in[7];
  const float* Wo  = (const float*)d_in[8];
  const float* lng = (const float*)d_in[9];
  const float* lnb = (const float*)d_in[10];
  float* out = (float*)d_out;

  float* ws  = (float*)d_ws;
  float* qb  = ws;                 // [B*H, T, 128]  (reused as out_pre after attention)
  float* kb  = ws + 4194304;       // [B*H, T, 128]
  float* vb  = ws + 8388608;       // [B*H, T, 128]
  float* yb  = ws + 12582912;      // [B, T, H*128]
  float* Gb  = ws + 16777216;      // [B*H, T]
  float* lmb = ws + 16809984;      // [B*H, T, 12]

  dim3 gproj(8, 32);  // N/128, M/128
  gemm_xwT<<<gproj, 256, 0, stream>>>(x, Wq, qb, MM, 1024, 1024, 1);
  gemm_xwT<<<gproj, 256, 0, stream>>>(x, Wk, kb, MM, 1024, 1024, 1);
  gemm_xwT<<<gproj, 256, 0, stream>>>(x, Wv, vb, MM, 1024, 1024, 1);
  proj_gl<<<MM, 128, 0, stream>>>(x, Wg, bg, Wdl, Lp, Gb, lmb);
  cumsum_k<<<BB*HH, 256, 0, stream>>>(Gb);
  attn_k<<<dim3(TT/32, BB*HH), 256, 0, stream>>>(qb, kb, vb, Gb, lmb, yb);
  gemm_xwT<<<gproj, 256, 0, stream>>>(yb, Wo, qb, MM, 1024, 1024, 0);  // out_pre -> qb
  ln_k<<<MM, 256, 0, stream>>>(qb, x, lng, lnb, out);
}

// Round 2
// 436.368 us; speedup vs baseline: 4.1920x; 4.1920x over previous
//
#include <hip/hip_runtime.h>
#include <math.h>

#define BB 2
#define TT 2048
#define HH 8
#define MM (BB*TT)   // 4096

typedef __attribute__((ext_vector_type(8))) short short8;
typedef __attribute__((ext_vector_type(4))) short short4v;
typedef __attribute__((ext_vector_type(4))) float f32x4;

__device__ __forceinline__ unsigned short f2bf(float f) {
  unsigned int u = __builtin_bit_cast(unsigned int, f);
  unsigned int r = (u + 0x7FFFu + ((u >> 16) & 1u)) >> 16;
  return (unsigned short)r;
}

__device__ __forceinline__ float softplus_f(float z) {
  return fmaxf(z, 0.f) + log1pf(expf(-fabsf(z)));
}

__device__ __forceinline__ void gload16(const void* g, void* lds) {
  __builtin_amdgcn_global_load_lds(
      (const __attribute__((address_space(1))) unsigned int*)g,
      (__attribute__((address_space(3))) unsigned int*)lds, 16, 0, 0);
}

// ---------- fused f32 -> bf16 conversion of x, Wq, Wk, Wv, Wo ----------
// dst layout: [xb(4M) | Wqb(1M) | Wkb(1M) | Wvb(1M) | Wob(1M)] contiguous.
__global__ __launch_bounds__(256) void cvt_all(
    const float* __restrict__ x, const float* __restrict__ wq,
    const float* __restrict__ wk, const float* __restrict__ wv,
    const float* __restrict__ wo, unsigned short* __restrict__ dst) {
  int i = (blockIdx.x * 256 + threadIdx.x) * 4;   // 8388608 total elems
  const float* src; int off;
  if (i < 4194304) { src = x; off = i; }
  else {
    int j = i - 4194304; int w = j >> 20; off = j & 1048575;
    src = (w == 0) ? wq : (w == 1) ? wk : (w == 2) ? wv : wo;
  }
  float4 v = *(const float4*)&src[off];
  unsigned long long p = (unsigned long long)f2bf(v.x)
                       | ((unsigned long long)f2bf(v.y) << 16)
                       | ((unsigned long long)f2bf(v.z) << 32)
                       | ((unsigned long long)f2bf(v.w) << 48);
  *(unsigned long long*)&dst[i] = p;
}

// ---------- bf16 MFMA GEMM: C = A[M,K] @ W[N,K]^T (m97 structure) ----------
// mode 0: C fp32 [m*N + n]
// mode 1: C bf16 head-split [((b*8+h)*2048 + t)*128 + d]
__global__ __launch_bounds__(256) void gemm_bf16(
    const unsigned short* __restrict__ A, const unsigned short* __restrict__ W,
    void* __restrict__ C, int M, int N, int K, int mode) {
  __shared__ unsigned short As[128 * 32];
  __shared__ unsigned short Bs[128 * 32];
  const int tid = threadIdx.x;
  const int l = tid & 63, w = tid >> 6;
  const int tl = l & 15, g4 = l >> 4;
  const int bm = blockIdx.y * 128, bn = blockIdx.x * 128;
  const int wm = (w & 1) * 64, wn = (w >> 1) * 64;
  f32x4 acc[4][4];
  #pragma unroll
  for (int i = 0; i < 4; ++i)
    #pragma unroll
    for (int j = 0; j < 4; ++j) acc[i][j] = (f32x4){0.f, 0.f, 0.f, 0.f};

  for (int k0 = 0; k0 < K; k0 += 32) {
    __syncthreads();   // prior tile reads complete
    #pragma unroll
    for (int p = 0; p < 2; ++p) {
      int fc = w * 128 + p * 64 + l;       // chunk id 0..511
      int r = fc >> 2, c = fc & 3;
      gload16(&A[(size_t)(bm + r) * K + k0 + c * 8], &As[(w * 128 + p * 64) * 8]);
      gload16(&W[(size_t)(bn + r) * K + k0 + c * 8], &Bs[(w * 128 + p * 64) * 8]);
    }
    __syncthreads();   // drains vmcnt (global_load_lds) per barrier semantics
    short8 a[4], b[4];
    #pragma unroll
    for (int mi = 0; mi < 4; ++mi)
      a[mi] = *(const short8*)&As[(wm + mi * 16 + tl) * 32 + g4 * 8];
    #pragma unroll
    for (int nj = 0; nj < 4; ++nj)
      b[nj] = *(const short8*)&Bs[(wn + nj * 16 + tl) * 32 + g4 * 8];
    #pragma unroll
    for (int mi = 0; mi < 4; ++mi)
      #pragma unroll
      for (int nj = 0; nj < 4; ++nj)
        acc[mi][nj] = __builtin_amdgcn_mfma_f32_16x16x32_bf16(a[mi], b[nj], acc[mi][nj], 0, 0, 0);
  }

  if (mode == 0) {
    float* Cf = (float*)C;
    #pragma unroll
    for (int mi = 0; mi < 4; ++mi)
      #pragma unroll
      for (int nj = 0; nj < 4; ++nj)
        #pragma unroll
        for (int r = 0; r < 4; ++r) {
          int row = bm + wm + mi * 16 + g4 * 4 + r;
          int col = bn + wn + nj * 16 + tl;
          Cf[(size_t)row * N + col] = acc[mi][nj][r];
        }
  } else {
    unsigned short* Cb = (unsigned short*)C;
    #pragma unroll
    for (int mi = 0; mi < 4; ++mi)
      #pragma unroll
      for (int r = 0; r < 4; ++r) {
        int m = bm + wm + mi * 16 + g4 * 4 + r;
        int bb = m >> 11, t = m & 2047;
        #pragma unroll
        for (int nj = 0; nj < 4; ++nj) {
          int n = bn + wn + nj * 16 + tl;
          int h = n >> 7, d = n & 127;
          Cb[((size_t)((bb * 8 + h) * 2048 + t)) * 128 + d] = f2bf(acc[mi][nj][r]);
        }
      }
  }
}

// ---------- small projections g / lambda (fp32, reads original x) ----------
__global__ __launch_bounds__(128) void proj_gl(
    const float* __restrict__ x, const float* __restrict__ Wg,
    const float* __restrict__ bg, const float* __restrict__ Wdl,
    const float* __restrict__ Lp, float* __restrict__ Gout,
    float* __restrict__ lamout) {
  __shared__ float xs[1024];
  const int m = blockIdx.x;
  const int tid = threadIdx.x;
  #pragma unroll
  for (int p = 0; p < 2; ++p) {
    float4 v = *(const float4*)&x[(size_t)m * 1024 + (tid + p * 128) * 4];
    *(float4*)&xs[(tid + p * 128) * 4] = v;
  }
  __syncthreads();
  if (tid < 104) {
    const float* wr = (tid < 8) ? &Wg[(size_t)tid * 1024] : &Wdl[(size_t)(tid - 8) * 1024];
    float dot = 0.f;
    for (int kk = 0; kk < 256; ++kk) {
      float4 w = *(const float4*)&wr[kk * 4];
      float4 xv = *(const float4*)&xs[kk * 4];
      dot += w.x * xv.x + w.y * xv.y + w.z * xv.z + w.w * xv.w;
    }
    int b = m >> 11, t = m & 2047;
    if (tid < 8) {
      Gout[(size_t)(b * 8 + tid) * 2048 + t] = -softplus_f(dot + bg[tid]);
    } else {
      int c = tid - 8, h = c / 12, lvl = c % 12;
      lamout[((size_t)(b * 8 + h) * 2048 + t) * 12 + lvl] = softplus_f(dot + Lp[h * 12 + lvl]);
    }
  }
}

// ---------- inclusive cumsum over T per (b,h) ----------
__global__ __launch_bounds__(256) void cumsum_k(float* __restrict__ G) {
  __shared__ float csum[256];
  const int bh = blockIdx.x;
  const int tid = threadIdx.x;
  float* Gr = G + (size_t)bh * 2048;
  float vals[8];
  float s = 0.f;
  #pragma unroll
  for (int j = 0; j < 8; ++j) { vals[j] = Gr[tid * 8 + j]; s += vals[j]; }
  csum[tid] = s;
  __syncthreads();
  if (tid == 0) {
    float run = 0.f;
    for (int i = 0; i < 256; ++i) { float t = csum[i]; csum[i] = run; run += t; }
  }
  __syncthreads();
  float run = csum[tid];
  #pragma unroll
  for (int j = 0; j < 8; ++j) { run += vals[j]; Gr[tid * 8 + j] = run; }
}

// ---------- MFMA attention ----------
// q,k,v: bf16 [B*H][2048][128]; G: f32 [B*H][2048]; lam: f32 [B*H][2048][12]
// y out: bf16 [B][2048][1024]
__global__ __launch_bounds__(256) void attn_mfma(
    const unsigned short* __restrict__ q, const unsigned short* __restrict__ k,
    const unsigned short* __restrict__ v, const float* __restrict__ G,
    const float* __restrict__ lam, unsigned short* __restrict__ y) {
  __shared__ unsigned short Ks[64 * 136];  // [s][d] pad->272B rows (16B aligned)
  __shared__ unsigned short Vt[128 * 72];  // [d][s] pad->144B rows
  __shared__ unsigned short Ss[64 * 72];   // [t][s] weighted scores bf16
  __shared__ float lamq[64 * 12];
  __shared__ float GsS[64];
  const int tid = threadIdx.x;
  const int l = tid & 63, w = tid >> 6;
  const int tl = l & 15, g4 = l >> 4;
  const int qt = 31 - (int)blockIdx.x;    // heavy q-tiles first
  const int bh = blockIdx.y;
  const int t0 = qt * 64;
  const unsigned short* qb = q + (size_t)bh * 2048 * 128;
  const unsigned short* kb = k + (size_t)bh * 2048 * 128;
  const unsigned short* vb = v + (size_t)bh * 2048 * 128;
  const float* Gb = G + (size_t)bh * 2048;
  const float* lamb = lam + (size_t)bh * 2048 * 12;

  const int qrow_loc = w * 16 + tl;          // 0..63 (lane's fixed query row)
  const int t_glob = t0 + qrow_loc;

  // hoist Q fragments (B-operand of swapped QK^T) + per-lane Gq
  short8 qf[4];
  #pragma unroll
  for (int c = 0; c < 4; ++c)
    qf[c] = *(const short8*)&qb[(size_t)t_glob * 128 + c * 32 + g4 * 8];
  const float gq = Gb[t_glob];

  for (int i = tid; i < 64 * 12; i += 256) lamq[i] = lamb[(size_t)t0 * 12 + i];

  f32x4 acc[8];
  #pragma unroll
  for (int nj = 0; nj < 8; ++nj) acc[nj] = (f32x4){0.f, 0.f, 0.f, 0.f};
  const float scale = 0.08838834764831845f;  // 1/sqrt(128)

  for (int st = 0; st <= qt; ++st) {
    const int s0 = st * 64;
    __syncthreads();   // prior PV reads of Ks/Vt/Ss done
    // stage K tile [64][136]
    #pragma unroll
    for (int p = 0; p < 4; ++p) {
      int fc = tid + p * 256;               // 0..1023 = 64 rows x 16 chunks
      int s = fc >> 4, ch = fc & 15;
      short8 kv = *(const short8*)&kb[(size_t)(s0 + s) * 128 + ch * 8];
      *(short8*)&Ks[s * 136 + ch * 8] = kv;
    }
    // stage V transposed [d][s]
    {
      int sq = (tid & 15) * 4, d0 = (tid >> 4) * 8;
      short8 r0 = *(const short8*)&vb[(size_t)(s0 + sq + 0) * 128 + d0];
      short8 r1 = *(const short8*)&vb[(size_t)(s0 + sq + 1) * 128 + d0];
      short8 r2 = *(const short8*)&vb[(size_t)(s0 + sq + 2) * 128 + d0];
      short8 r3 = *(const short8*)&vb[(size_t)(s0 + sq + 3) * 128 + d0];
      #pragma unroll
      for (int j = 0; j < 8; ++j) {
        short4v pk = {r0[j], r1[j], r2[j], r3[j]};
        *(short4v*)&Vt[(d0 + j) * 72 + sq] = pk;
      }
    }
    if (tid < 64) GsS[tid] = Gb[s0 + tid];
    __syncthreads();

    // swapped QK^T: D[s, t] = sum_d K[s,d] Q[t,d]; lane owns col t
    #pragma unroll
    for (int sb = 0; sb < 4; ++sb) {
      f32x4 sc = (f32x4){0.f, 0.f, 0.f, 0.f};
      #pragma unroll
      for (int c = 0; c < 4; ++c) {
        short8 kf = *(const short8*)&Ks[(sb * 16 + tl) * 136 + c * 32 + g4 * 8];
        sc = __builtin_amdgcn_mfma_f32_16x16x32_bf16(kf, qf[c], sc, 0, 0, 0);
      }
      short sw[4];
      #pragma unroll
      for (int r = 0; r < 4; ++r) {
        int s_loc = sb * 16 + g4 * 4 + r;
        int dts = t_glob - (s0 + s_loc);
        float val = 0.f;
        if (dts >= 0) {
          int lvl = (dts == 0) ? 0 : min(32 - __clz(dts), 11);
          val = sc[r] * scale * __expf(gq - GsS[s_loc]) * lamq[qrow_loc * 12 + lvl];
        }
        sw[r] = (short)f2bf(val);
      }
      short4v pk = {sw[0], sw[1], sw[2], sw[3]};
      *(short4v*)&Ss[qrow_loc * 72 + sb * 16 + g4 * 4] = pk;
    }
    __syncthreads();

    // PV: Y[t,d] += S[t,s] V[s,d]; A-frag from Ss (own wave rows), B from Vt
    #pragma unroll
    for (int ks = 0; ks < 2; ++ks) {
      short8 af = *(const short8*)&Ss[(w * 16 + tl) * 72 + ks * 32 + g4 * 8];
      #pragma unroll
      for (int nj = 0; nj < 8; ++nj) {
        short8 bf = *(const short8*)&Vt[(nj * 16 + tl) * 72 + ks * 32 + g4 * 8];
        acc[nj] = __builtin_amdgcn_mfma_f32_16x16x32_bf16(af, bf, acc[nj], 0, 0, 0);
      }
    }
  }

  // write y bf16 [B,T,1024]
  const int b = bh >> 3, h = bh & 7;
  #pragma unroll
  for (int nj = 0; nj < 8; ++nj) {
    int d = nj * 16 + tl;
    #pragma unroll
    for (int r = 0; r < 4; ++r) {
      int tg = t0 + w * 16 + g4 * 4 + r;
      y[((size_t)(b * 2048 + tg)) * 1024 + h * 128 + d] = f2bf(acc[nj][r]);
    }
  }
}

// ---------- residual + LayerNorm ----------
__global__ __launch_bounds__(256) void ln_k(
    const float* __restrict__ op, const float* __restrict__ x,
    const float* __restrict__ g, const float* __restrict__ b,
    float* __restrict__ out) {
  const int m = blockIdx.x;
  const int tid = threadIdx.x;
  float4 o = *(const float4*)&op[(size_t)m * 1024 + tid * 4];
  float4 xv = *(const float4*)&x[(size_t)m * 1024 + tid * 4];
  float v0 = o.x + xv.x, v1 = o.y + xv.y, v2 = o.z + xv.z, v3 = o.w + xv.w;
  float s1 = v0 + v1 + v2 + v3;
  float s2 = v0 * v0 + v1 * v1 + v2 * v2 + v3 * v3;
  #pragma unroll
  for (int off = 32; off >= 1; off >>= 1) {
    s1 += __shfl_down(s1, off);
    s2 += __shfl_down(s2, off);
  }
  __shared__ float r1[4], r2[4];
  if ((tid & 63) == 0) { r1[tid >> 6] = s1; r2[tid >> 6] = s2; }
  __syncthreads();
  float S1 = r1[0] + r1[1] + r1[2] + r1[3];
  float S2 = r2[0] + r2[1] + r2[2] + r2[3];
  float mu = S1 * (1.f / 1024.f);
  float var = S2 * (1.f / 1024.f) - mu * mu;
  float rs = rsqrtf(var + 1e-5f);
  float4 gg = *(const float4*)&g[tid * 4];
  float4 bb = *(const float4*)&b[tid * 4];
  float4 r;
  r.x = (v0 - mu) * rs * gg.x + bb.x;
  r.y = (v1 - mu) * rs * gg.y + bb.y;
  r.z = (v2 - mu) * rs * gg.z + bb.z;
  r.w = (v3 - mu) * rs * gg.w + bb.w;
  *(float4*)&out[(size_t)m * 1024 + tid * 4] = r;
}

extern "C" void kernel_launch(void* const* d_in, const int* in_sizes, int n_in,
                              void* d_out, int out_size, void* d_ws, size_t ws_size,
                              hipStream_t stream) {
  const float* x   = (const float*)d_in[0];
  const float* Wq  = (const float*)d_in[1];
  const float* Wk  = (const float*)d_in[2];
  const float* Wv  = (const float*)d_in[3];
  const float* Wg  = (const float*)d_in[4];
  const float* bg  = (const float*)d_in[5];
  const float* Wdl = (const float*)d_in[6];
  const float* Lp  = (const float*)d_in[7];
  const float* Wo  = (const float*)d_in[8];
  const float* lng = (const float*)d_in[9];
  const float* lnb = (const float*)d_in[10];
  float* out = (float*)d_out;

  unsigned short* wsb = (unsigned short*)d_ws;
  unsigned short* xb  = wsb;                    // 4194304 bf16
  unsigned short* Wqb = wsb + 4194304;          // 1048576 each, contiguous after xb
  unsigned short* Wkb = Wqb + 1048576;
  unsigned short* Wvb = Wkb + 1048576;
  unsigned short* Wob = Wvb + 1048576;
  unsigned short* qbf = Wob + 1048576;          // [16][2048][128] bf16
  unsigned short* kbf = qbf + 4194304;
  unsigned short* vbf = kbf + 4194304;
  unsigned short* ybf = vbf + 4194304;          // [2][2048][1024] bf16
  float* outp  = (float*)(wsb + 25165824);      // 4194304 f32
  float* Gb2   = outp + 4194304;                // 32768 f32
  float* lamb2 = Gb2 + 32768;                   // 393216 f32

  cvt_all<<<8192, 256, 0, stream>>>(x, Wq, Wk, Wv, Wo, wsb);

  dim3 gproj(8, 32);  // N/128, M/128
  gemm_bf16<<<gproj, 256, 0, stream>>>(xb, Wqb, qbf, MM, 1024, 1024, 1);
  gemm_bf16<<<gproj, 256, 0, stream>>>(xb, Wkb, kbf, MM, 1024, 1024, 1);
  gemm_bf16<<<gproj, 256, 0, stream>>>(xb, Wvb, vbf, MM, 1024, 1024, 1);
  proj_gl<<<MM, 128, 0, stream>>>(x, Wg, bg, Wdl, Lp, Gb2, lamb2);
  cumsum_k<<<BB * HH, 256, 0, stream>>>(Gb2);
  attn_mfma<<<dim3(32, 16), 256, 0, stream>>>(qbf, kbf, vbf, Gb2, lamb2, ybf);
  gemm_bf16<<<gproj, 256, 0, stream>>>(ybf, Wob, outp, MM, 1024, 1024, 0);
  ln_k<<<MM, 256, 0, stream>>>(outp, x, lng, lnb, out);
}